// Round 1
// baseline (109.706 us; speedup 1.0000x reference)
//
#include <hip/hip_runtime.h>
#include <math.h>

#define NB 16
#define CB 256
#define HB 64
#define WB 64
#define MIP 8
#define EPSV 1e-5f

// K1: per (n,c) plane: compute row means (over w) -> xh, col means (over h) -> xw
__global__ __launch_bounds__(256) void k_reduce(const float* __restrict__ x,
                                                const float* __restrict__ res,
                                                float* __restrict__ xh,
                                                float* __restrict__ xw) {
    int plane = blockIdx.x;                       // n*256 + c
    const float* px = x   + (size_t)plane * 4096;
    const float* pr = res + (size_t)plane * 4096;
    __shared__ float s[64 * 65];                  // padded stride 65
    int t = threadIdx.x;
    int r  = t >> 2;
    int cb = (t & 3) << 4;                        // 16 floats per thread
    const float4* px4 = (const float4*)(px + r * 64 + cb);
    const float4* pr4 = (const float4*)(pr + r * 64 + cb);
#pragma unroll
    for (int i = 0; i < 4; i++) {
        float4 a = px4[i];
        float4 b = pr4[i];
        float* d = &s[r * 65 + cb + i * 4];
        d[0] = a.x + b.x; d[1] = a.y + b.y; d[2] = a.z + b.z; d[3] = a.w + b.w;
    }
    __syncthreads();
    if (t < 64) {
        // column sums over rows -> xw (mean over h)
        float acc = 0.f;
#pragma unroll
        for (int rr = 0; rr < 64; rr++) acc += s[rr * 65 + t];
        xw[(size_t)plane * 64 + t] = acc * (1.f / 64.f);
    } else if (t < 128) {
        // row sums over cols -> xh (mean over w)
        int rr = t - 64;
        float acc = 0.f;
#pragma unroll
        for (int c = 0; c < 64; c++) acc += s[rr * 65 + c];
        xh[(size_t)plane * 64 + rr] = acc * (1.f / 64.f);
    }
}

// K2: per n: y = hswish(BN(W1*pool + b1)); a_h = sigmoid(W2*yh + b2); a_w = sigmoid(W3*yw + b3)
__global__ __launch_bounds__(256) void k_mid(const float* __restrict__ xh,
                                             const float* __restrict__ xw,
                                             const float* __restrict__ w1,
                                             const float* __restrict__ b1,
                                             const float* __restrict__ gamma,
                                             const float* __restrict__ beta,
                                             const float* __restrict__ mean,
                                             const float* __restrict__ var,
                                             const float* __restrict__ w2,
                                             const float* __restrict__ b2,
                                             const float* __restrict__ w3,
                                             const float* __restrict__ b3,
                                             float* __restrict__ ah,
                                             float* __restrict__ aw) {
    int n = blockIdx.x;
    int t = threadIdx.x;
    __shared__ float yl[MIP * 128];

    // Phase A: y[m][p], p in [0,128): p<64 from xh, else xw. Each thread: one p, 4 m's.
    int p  = t & 127;
    int mg = (t >> 7) * 4;  // 0 or 4
    const float* pool = (p < 64) ? (xh + (size_t)n * CB * 64 + p)
                                 : (xw + (size_t)n * CB * 64 + (p - 64));
    float acc[4] = {0.f, 0.f, 0.f, 0.f};
    for (int c = 0; c < CB; c++) {
        float pv = pool[(size_t)c * 64];
#pragma unroll
        for (int k = 0; k < 4; k++) acc[k] += pv * w1[(mg + k) * CB + c];
    }
#pragma unroll
    for (int k = 0; k < 4; k++) {
        int m = mg + k;
        float yv = acc[k] + b1[m];
        float inv = gamma[m] * rsqrtf(var[m] + EPSV);
        yv = (yv - mean[m]) * inv + beta[m];
        float cl = fminf(fmaxf(yv + 3.f, 0.f), 6.f);
        yl[m * 128 + p] = yv * cl * (1.f / 6.f);
    }
    __syncthreads();

    // Phase B: a_h[n][o][hh], a_w[n][o][ww]; 16384 outputs each per n.
    for (int j = 0; j < 64; j++) {
        int idx = j * 256 + t;
        int o  = idx >> 6;
        int hh = idx & 63;
        float acch = b2[o];
        float accw = b3[o];
#pragma unroll
        for (int m = 0; m < MIP; m++) {
            acch += yl[m * 128 + hh]      * w2[o * MIP + m];
            accw += yl[m * 128 + 64 + hh] * w3[o * MIP + m];
        }
        ah[((size_t)n * CB + o) * 64 + hh] = 1.f / (1.f + __expf(-acch));
        aw[((size_t)n * CB + o) * 64 + hh] = 1.f / (1.f + __expf(-accw));
    }
}

// K3: out = 2*wei*x + 2*res, wei = ah[h]*aw[w] per plane
__global__ __launch_bounds__(256) void k_apply(const float* __restrict__ x,
                                               const float* __restrict__ res,
                                               const float* __restrict__ ah,
                                               const float* __restrict__ aw,
                                               float* __restrict__ out) {
    int plane = blockIdx.x;
    const float* px = x   + (size_t)plane * 4096;
    const float* pr = res + (size_t)plane * 4096;
    float*       po = out + (size_t)plane * 4096;
    __shared__ float sah[64], saw[64];
    int t = threadIdx.x;
    if (t < 64)       sah[t]      = ah[(size_t)plane * 64 + t];
    else if (t < 128) saw[t - 64] = aw[(size_t)plane * 64 + (t - 64)];
    __syncthreads();
    int r  = t >> 2;
    int cb = (t & 3) << 4;
    float ahr2 = 2.f * sah[r];
    const float4* px4 = (const float4*)(px + r * 64 + cb);
    const float4* pr4 = (const float4*)(pr + r * 64 + cb);
    float4*       po4 = (float4*)(po + r * 64 + cb);
#pragma unroll
    for (int i = 0; i < 4; i++) {
        float4 a = px4[i];
        float4 b = pr4[i];
        float w0 = ahr2 * saw[cb + i * 4 + 0];
        float w1v = ahr2 * saw[cb + i * 4 + 1];
        float w2v = ahr2 * saw[cb + i * 4 + 2];
        float w3v = ahr2 * saw[cb + i * 4 + 3];
        float4 o;
        o.x = a.x * w0  + 2.f * b.x;
        o.y = a.y * w1v + 2.f * b.y;
        o.z = a.z * w2v + 2.f * b.z;
        o.w = a.w * w3v + 2.f * b.w;
        po4[i] = o;
    }
}

extern "C" void kernel_launch(void* const* d_in, const int* in_sizes, int n_in,
                              void* d_out, int out_size, void* d_ws, size_t ws_size,
                              hipStream_t stream) {
    const float* x     = (const float*)d_in[0];
    const float* res   = (const float*)d_in[1];
    const float* w1    = (const float*)d_in[2];
    const float* b1    = (const float*)d_in[3];
    const float* gamma = (const float*)d_in[4];
    const float* beta  = (const float*)d_in[5];
    const float* mean  = (const float*)d_in[6];
    const float* var   = (const float*)d_in[7];
    const float* w2    = (const float*)d_in[8];
    const float* b2    = (const float*)d_in[9];
    const float* w3    = (const float*)d_in[10];
    const float* b3    = (const float*)d_in[11];
    float* out = (float*)d_out;

    float* ws = (float*)d_ws;
    float* xh = ws;                 // 16*256*64 = 262144
    float* xw = ws + 262144;
    float* ah = ws + 524288;
    float* aw = ws + 786432;        // total 4 MiB

    k_reduce<<<NB * CB, 256, 0, stream>>>(x, res, xh, xw);
    k_mid<<<NB, 256, 0, stream>>>(xh, xw, w1, b1, gamma, beta, mean, var,
                                  w2, b2, w3, b3, ah, aw);
    k_apply<<<NB * CB, 256, 0, stream>>>(x, res, ah, aw, out);
}

// Round 2
// 81.701 us; speedup vs baseline: 1.3428x; 1.3428x over previous
//
#include <hip/hip_runtime.h>
#include <math.h>

#define NB 16
#define CB 256
#define MIP 8
#define EPSV 1e-5f

// K1: per (n,c) plane: row means (over w) -> xh[n][c][h], col means (over h) -> xw[n][c][w]
__global__ __launch_bounds__(256) void k_reduce(const float* __restrict__ x,
                                                const float* __restrict__ res,
                                                float* __restrict__ xh,
                                                float* __restrict__ xw) {
    int plane = blockIdx.x;                       // n*256 + c
    const float* px = x   + (size_t)plane * 4096;
    const float* pr = res + (size_t)plane * 4096;
    __shared__ float s[64 * 65];                  // padded stride 65
    int t = threadIdx.x;
    int r  = t >> 2;
    int cb = (t & 3) << 4;                        // 16 floats per thread
    const float4* px4 = (const float4*)(px + r * 64 + cb);
    const float4* pr4 = (const float4*)(pr + r * 64 + cb);
#pragma unroll
    for (int i = 0; i < 4; i++) {
        float4 a = px4[i];
        float4 b = pr4[i];
        float* d = &s[r * 65 + cb + i * 4];
        d[0] = a.x + b.x; d[1] = a.y + b.y; d[2] = a.z + b.z; d[3] = a.w + b.w;
    }
    __syncthreads();
    if (t < 64) {
        // column sums over rows -> xw (mean over h)
        float acc = 0.f;
#pragma unroll
        for (int rr = 0; rr < 64; rr++) acc += s[rr * 65 + t];
        xw[(size_t)plane * 64 + t] = acc * (1.f / 64.f);
    } else if (t < 128) {
        // row sums over cols -> xh (mean over w)
        int rr = t - 64;
        float acc = 0.f;
#pragma unroll
        for (int c = 0; c < 64; c++) acc += s[rr * 65 + c];
        xh[(size_t)plane * 64 + rr] = acc * (1.f / 64.f);
    }
}

// K2: per n: yl[n][m][p] = hswish(BN(W1*pool + b1)), p in [0,128)  (p<64: from xh, else xw)
__global__ __launch_bounds__(256) void k_mid_a(const float* __restrict__ xh,
                                               const float* __restrict__ xw,
                                               const float* __restrict__ w1,
                                               const float* __restrict__ b1,
                                               const float* __restrict__ gamma,
                                               const float* __restrict__ beta,
                                               const float* __restrict__ mean,
                                               const float* __restrict__ var,
                                               float* __restrict__ yl) {
    int n = blockIdx.x;
    int t = threadIdx.x;
    int p  = t & 127;
    int mg = (t >> 7) * 4;  // 0 or 4 (wave-uniform)
    const float* pool = (p < 64) ? (xh + (size_t)n * CB * 64 + p)
                                 : (xw + (size_t)n * CB * 64 + (p - 64));
    float acc[4] = {0.f, 0.f, 0.f, 0.f};
    for (int c = 0; c < CB; c++) {
        float pv = pool[(size_t)c * 64];
#pragma unroll
        for (int k = 0; k < 4; k++) acc[k] += pv * w1[(mg + k) * CB + c];
    }
#pragma unroll
    for (int k = 0; k < 4; k++) {
        int m = mg + k;
        float yv = acc[k] + b1[m];
        float inv = gamma[m] * rsqrtf(var[m] + EPSV);
        yv = (yv - mean[m]) * inv + beta[m];
        float cl = fminf(fmaxf(yv + 3.f, 0.f), 6.f);
        yl[((size_t)n * MIP + m) * 128 + p] = yv * cl * (1.f / 6.f);
    }
}

// K3: per (n,o) plane: prologue computes ah[h], aw[w] from yl/w2/w3, then
//     out = 2*wei*x + 2*res, wei = ah[h]*aw[w]
__global__ __launch_bounds__(256) void k_apply(const float* __restrict__ x,
                                               const float* __restrict__ res,
                                               const float* __restrict__ yl,
                                               const float* __restrict__ w2,
                                               const float* __restrict__ b2,
                                               const float* __restrict__ w3,
                                               const float* __restrict__ b3,
                                               float* __restrict__ out) {
    int plane = blockIdx.x;                       // n*256 + o
    int n = plane >> 8;
    int o = plane & 255;
    const float* px = x   + (size_t)plane * 4096;
    const float* pr = res + (size_t)plane * 4096;
    float*       po = out + (size_t)plane * 4096;
    __shared__ float sah[64], saw[64];
    int t = threadIdx.x;
    if (t < 128) {
        int hh  = t & 63;
        int off = (t < 64) ? 0 : 64;
        const float* wv = (t < 64) ? (w2 + o * MIP) : (w3 + o * MIP);
        float acc = (t < 64) ? b2[o] : b3[o];
        const float* ylp = yl + (size_t)n * MIP * 128 + off + hh;
#pragma unroll
        for (int m = 0; m < MIP; m++) acc += ylp[m * 128] * wv[m];
        float sig = 1.f / (1.f + __expf(-acc));
        if (t < 64) sah[hh] = sig; else saw[hh] = sig;
    }
    __syncthreads();
    int r  = t >> 2;
    int cb = (t & 3) << 4;
    float ahr2 = 2.f * sah[r];
    const float4* px4 = (const float4*)(px + r * 64 + cb);
    const float4* pr4 = (const float4*)(pr + r * 64 + cb);
    float4*       po4 = (float4*)(po + r * 64 + cb);
#pragma unroll
    for (int i = 0; i < 4; i++) {
        float4 a = px4[i];
        float4 b = pr4[i];
        float w0  = ahr2 * saw[cb + i * 4 + 0];
        float w1v = ahr2 * saw[cb + i * 4 + 1];
        float w2v = ahr2 * saw[cb + i * 4 + 2];
        float w3v = ahr2 * saw[cb + i * 4 + 3];
        float4 oo;
        oo.x = a.x * w0  + 2.f * b.x;
        oo.y = a.y * w1v + 2.f * b.y;
        oo.z = a.z * w2v + 2.f * b.z;
        oo.w = a.w * w3v + 2.f * b.w;
        po4[i] = oo;
    }
}

extern "C" void kernel_launch(void* const* d_in, const int* in_sizes, int n_in,
                              void* d_out, int out_size, void* d_ws, size_t ws_size,
                              hipStream_t stream) {
    const float* x     = (const float*)d_in[0];
    const float* res   = (const float*)d_in[1];
    const float* w1    = (const float*)d_in[2];
    const float* b1    = (const float*)d_in[3];
    const float* gamma = (const float*)d_in[4];
    const float* beta  = (const float*)d_in[5];
    const float* mean  = (const float*)d_in[6];
    const float* var   = (const float*)d_in[7];
    const float* w2    = (const float*)d_in[8];
    const float* b2    = (const float*)d_in[9];
    const float* w3    = (const float*)d_in[10];
    const float* b3    = (const float*)d_in[11];
    float* out = (float*)d_out;

    float* ws = (float*)d_ws;
    float* xh = ws;                 // 16*256*64 = 262144 floats
    float* xw = ws + 262144;        // 262144 floats
    float* yl = ws + 524288;        // 16*8*128 = 16384 floats

    k_reduce<<<NB * CB, 256, 0, stream>>>(x, res, xh, xw);
    k_mid_a<<<NB, 256, 0, stream>>>(xh, xw, w1, b1, gamma, beta, mean, var, yl);
    k_apply<<<NB * CB, 256, 0, stream>>>(x, res, yl, w2, b2, w3, b3, out);
}

// Round 3
// 81.580 us; speedup vs baseline: 1.3448x; 1.0015x over previous
//
#include <hip/hip_runtime.h>
#include <math.h>

#define NB 16
#define CB 256
#define MIP 8
#define EPSV 1e-5f

// K1: per (n,c) plane: row means (over w) -> xh[n][c][h], col means (over h) -> xw[n][c][w]
// Rows: register partial + 4-lane shfl_xor reduce (no LDS).
// Cols: LDS tile transpose, all 256 threads, 16-deep chains only.
__global__ __launch_bounds__(256) void k_reduce(const float* __restrict__ x,
                                                const float* __restrict__ res,
                                                float* __restrict__ xh,
                                                float* __restrict__ xw) {
    int plane = blockIdx.x;                       // n*256 + c
    const float* px = x   + (size_t)plane * 4096;
    const float* pr = res + (size_t)plane * 4096;
    __shared__ float s[64 * 65];                  // padded stride 65
    __shared__ float spad[256];
    int t  = threadIdx.x;
    int r  = t >> 2;                              // row 0..63
    int cq = t & 3;
    int cb = cq << 4;                             // 16 floats per thread
    const float4* px4 = (const float4*)(px + r * 64 + cb);
    const float4* pr4 = (const float4*)(pr + r * 64 + cb);
    float v[16];
    float rsum = 0.f;
#pragma unroll
    for (int i = 0; i < 4; i++) {
        float4 a = px4[i];
        float4 b = pr4[i];
        v[i*4+0] = a.x + b.x; v[i*4+1] = a.y + b.y;
        v[i*4+2] = a.z + b.z; v[i*4+3] = a.w + b.w;
        rsum += v[i*4+0] + v[i*4+1] + v[i*4+2] + v[i*4+3];
    }
    // row sum across the 4 lanes sharing this row
    rsum += __shfl_xor(rsum, 1);
    rsum += __shfl_xor(rsum, 2);
    if (cq == 0) xh[(size_t)plane * 64 + r] = rsum * 0.015625f;

    // stage values for the column transpose
#pragma unroll
    for (int i = 0; i < 16; i++) s[r * 65 + cb + i] = v[i];
    __syncthreads();

    // column partials: thread (q, col) sums rows 16q..16q+15 of column col
    int col = t & 63;
    int q   = t >> 6;
    float csum = 0.f;
#pragma unroll
    for (int i = 0; i < 16; i++) csum += s[(q * 16 + i) * 65 + col];
    spad[q * 64 + col] = csum;
    __syncthreads();
    if (t < 64)
        xw[(size_t)plane * 64 + t] =
            (spad[t] + spad[64 + t] + spad[128 + t] + spad[192 + t]) * 0.015625f;
}

// K2: per n: yl[n][m][p] = hswish(BN(W1*pool + b1)), p in [0,128)  (p<64: from xh, else xw)
__global__ __launch_bounds__(256) void k_mid_a(const float* __restrict__ xh,
                                               const float* __restrict__ xw,
                                               const float* __restrict__ w1,
                                               const float* __restrict__ b1,
                                               const float* __restrict__ gamma,
                                               const float* __restrict__ beta,
                                               const float* __restrict__ mean,
                                               const float* __restrict__ var,
                                               float* __restrict__ yl) {
    int n = blockIdx.x;
    int t = threadIdx.x;
    int p  = t & 127;
    int mg = (t >> 7) * 4;  // 0 or 4 (wave-uniform)
    const float* pool = (p < 64) ? (xh + (size_t)n * CB * 64 + p)
                                 : (xw + (size_t)n * CB * 64 + (p - 64));
    float acc[4] = {0.f, 0.f, 0.f, 0.f};
    for (int c = 0; c < CB; c++) {
        float pv = pool[(size_t)c * 64];
#pragma unroll
        for (int k = 0; k < 4; k++) acc[k] += pv * w1[(mg + k) * CB + c];
    }
#pragma unroll
    for (int k = 0; k < 4; k++) {
        int m = mg + k;
        float yv = acc[k] + b1[m];
        float inv = gamma[m] * rsqrtf(var[m] + EPSV);
        yv = (yv - mean[m]) * inv + beta[m];
        float cl = fminf(fmaxf(yv + 3.f, 0.f), 6.f);
        yl[((size_t)n * MIP + m) * 128 + p] = yv * cl * (1.f / 6.f);
    }
}

// K3: per (n,o) plane: prologue computes ah[h], aw[w] from yl/w2/w3, then
//     out = 2*wei*x + 2*res, wei = ah[h]*aw[w]
__global__ __launch_bounds__(256) void k_apply(const float* __restrict__ x,
                                               const float* __restrict__ res,
                                               const float* __restrict__ yl,
                                               const float* __restrict__ w2,
                                               const float* __restrict__ b2,
                                               const float* __restrict__ w3,
                                               const float* __restrict__ b3,
                                               float* __restrict__ out) {
    int plane = blockIdx.x;                       // n*256 + o
    int n = plane >> 8;
    int o = plane & 255;
    const float* px = x   + (size_t)plane * 4096;
    const float* pr = res + (size_t)plane * 4096;
    float*       po = out + (size_t)plane * 4096;
    __shared__ float sah[64], saw[64];
    int t = threadIdx.x;
    if (t < 128) {
        int hh  = t & 63;
        int off = (t < 64) ? 0 : 64;
        const float* wv = (t < 64) ? (w2 + o * MIP) : (w3 + o * MIP);
        float acc = (t < 64) ? b2[o] : b3[o];
        const float* ylp = yl + (size_t)n * MIP * 128 + off + hh;
#pragma unroll
        for (int m = 0; m < MIP; m++) acc += ylp[m * 128] * wv[m];
        float sig = 1.f / (1.f + __expf(-acc));
        if (t < 64) sah[hh] = sig; else saw[hh] = sig;
    }
    __syncthreads();
    int r  = t >> 2;
    int cb = (t & 3) << 4;
    float ahr2 = 2.f * sah[r];
    const float4* px4 = (const float4*)(px + r * 64 + cb);
    const float4* pr4 = (const float4*)(pr + r * 64 + cb);
    float4*       po4 = (float4*)(po + r * 64 + cb);
#pragma unroll
    for (int i = 0; i < 4; i++) {
        float4 a = px4[i];
        float4 b = pr4[i];
        float w0  = ahr2 * saw[cb + i * 4 + 0];
        float w1v = ahr2 * saw[cb + i * 4 + 1];
        float w2v = ahr2 * saw[cb + i * 4 + 2];
        float w3v = ahr2 * saw[cb + i * 4 + 3];
        float4 oo;
        oo.x = a.x * w0  + 2.f * b.x;
        oo.y = a.y * w1v + 2.f * b.y;
        oo.z = a.z * w2v + 2.f * b.z;
        oo.w = a.w * w3v + 2.f * b.w;
        po4[i] = oo;
    }
}

extern "C" void kernel_launch(void* const* d_in, const int* in_sizes, int n_in,
                              void* d_out, int out_size, void* d_ws, size_t ws_size,
                              hipStream_t stream) {
    const float* x     = (const float*)d_in[0];
    const float* res   = (const float*)d_in[1];
    const float* w1    = (const float*)d_in[2];
    const float* b1    = (const float*)d_in[3];
    const float* gamma = (const float*)d_in[4];
    const float* beta  = (const float*)d_in[5];
    const float* mean  = (const float*)d_in[6];
    const float* var   = (const float*)d_in[7];
    const float* w2    = (const float*)d_in[8];
    const float* b2    = (const float*)d_in[9];
    const float* w3    = (const float*)d_in[10];
    const float* b3    = (const float*)d_in[11];
    float* out = (float*)d_out;

    float* ws = (float*)d_ws;
    float* xh = ws;                 // 16*256*64 = 262144 floats
    float* xw = ws + 262144;        // 262144 floats
    float* yl = ws + 524288;        // 16*8*128 = 16384 floats

    k_reduce<<<NB * CB, 256, 0, stream>>>(x, res, xh, xw);
    k_mid_a<<<NB, 256, 0, stream>>>(xh, xw, w1, b1, gamma, beta, mean, var, yl);
    k_apply<<<NB * CB, 256, 0, stream>>>(x, res, yl, w2, b2, w3, b3, out);
}

// Round 4
// 75.013 us; speedup vs baseline: 1.4625x; 1.0875x over previous
//
#include <hip/hip_runtime.h>
#include <math.h>

#define NB 16
#define CB 256
#define MIP 8
#define EPSV 1e-5f

// K1: per (n,c) plane: row means (over w) -> xh[n][c][h], col means (over h) -> xw[n][c][w]
// Lane-contiguous loads: thread t, iter i -> float4 at element (i*256+t)*4.
// Row r = i*16 + (t>>4): 16 consecutive lanes share a row (shfl_xor 1,2,4,8).
// Cols 4*(t&15)..+3: fixed across i -> register csum, shfl_xor 16,32 + LDS combine.
__global__ __launch_bounds__(256) void k_reduce(const float* __restrict__ x,
                                                const float* __restrict__ res,
                                                float* __restrict__ xh,
                                                float* __restrict__ xw) {
    int plane = blockIdx.x;                       // n*256 + c
    const float4* px4 = (const float4*)(x   + (size_t)plane * 4096);
    const float4* pr4 = (const float4*)(res + (size_t)plane * 4096);
    __shared__ float spad[256];
    int t = threadIdx.x;
    float csum0 = 0.f, csum1 = 0.f, csum2 = 0.f, csum3 = 0.f;
    float rpart[4];
#pragma unroll
    for (int i = 0; i < 4; i++) {
        float4 a = px4[i * 256 + t];
        float4 b = pr4[i * 256 + t];
        float s0 = a.x + b.x, s1 = a.y + b.y, s2 = a.z + b.z, s3 = a.w + b.w;
        csum0 += s0; csum1 += s1; csum2 += s2; csum3 += s3;
        float rs = (s0 + s1) + (s2 + s3);
        rs += __shfl_xor(rs, 1);
        rs += __shfl_xor(rs, 2);
        rs += __shfl_xor(rs, 4);
        rs += __shfl_xor(rs, 8);
        rpart[i] = rs;
    }
    if ((t & 15) == 0) {
        int g = t >> 4;                           // 0..15
#pragma unroll
        for (int i = 0; i < 4; i++)
            xh[(size_t)plane * 64 + i * 16 + g] = rpart[i] * 0.015625f;
    }
    // column partials: thread covers cols 4*(t&15)..+3 over rows {i*16 + (t>>4)}
    // combine the 4 row-groups within each wave (lanes differing in bits 4,5)
    csum0 += __shfl_xor(csum0, 16); csum0 += __shfl_xor(csum0, 32);
    csum1 += __shfl_xor(csum1, 16); csum1 += __shfl_xor(csum1, 32);
    csum2 += __shfl_xor(csum2, 16); csum2 += __shfl_xor(csum2, 32);
    csum3 += __shfl_xor(csum3, 16); csum3 += __shfl_xor(csum3, 32);
    int wv = t >> 6;                              // wave 0..3
    int j  = t & 15;
    if ((t & 63) < 16) {
        float* d = &spad[wv * 64 + j * 4];
        d[0] = csum0; d[1] = csum1; d[2] = csum2; d[3] = csum3;
    }
    __syncthreads();
    if (t < 64)
        xw[(size_t)plane * 64 + t] =
            (spad[t] + spad[64 + t] + spad[128 + t] + spad[192 + t]) * 0.015625f;
}

// K2: per n: yl[n][m][p] = hswish(BN(W1*pool + b1)), p in [0,128)  (p<64: from xh, else xw)
__global__ __launch_bounds__(256) void k_mid_a(const float* __restrict__ xh,
                                               const float* __restrict__ xw,
                                               const float* __restrict__ w1,
                                               const float* __restrict__ b1,
                                               const float* __restrict__ gamma,
                                               const float* __restrict__ beta,
                                               const float* __restrict__ mean,
                                               const float* __restrict__ var,
                                               float* __restrict__ yl) {
    int n = blockIdx.x;
    int t = threadIdx.x;
    int p  = t & 127;
    int mg = (t >> 7) * 4;  // 0 or 4 (wave-uniform)
    const float* pool = (p < 64) ? (xh + (size_t)n * CB * 64 + p)
                                 : (xw + (size_t)n * CB * 64 + (p - 64));
    float acc[4] = {0.f, 0.f, 0.f, 0.f};
    for (int c = 0; c < CB; c++) {
        float pv = pool[(size_t)c * 64];
#pragma unroll
        for (int k = 0; k < 4; k++) acc[k] += pv * w1[(mg + k) * CB + c];
    }
#pragma unroll
    for (int k = 0; k < 4; k++) {
        int m = mg + k;
        float yv = acc[k] + b1[m];
        float inv = gamma[m] * rsqrtf(var[m] + EPSV);
        yv = (yv - mean[m]) * inv + beta[m];
        float cl = fminf(fmaxf(yv + 3.f, 0.f), 6.f);
        yl[((size_t)n * MIP + m) * 128 + p] = yv * cl * (1.f / 6.f);
    }
}

// K3: per (n,o) plane: prologue computes ah[h], aw[w] from yl/w2/w3, then
//     out = 2*wei*x + 2*res, wei = ah[h]*aw[w].  Lane-contiguous main loop.
__global__ __launch_bounds__(256) void k_apply(const float* __restrict__ x,
                                               const float* __restrict__ res,
                                               const float* __restrict__ yl,
                                               const float* __restrict__ w2,
                                               const float* __restrict__ b2,
                                               const float* __restrict__ w3,
                                               const float* __restrict__ b3,
                                               float* __restrict__ out) {
    int plane = blockIdx.x;                       // n*256 + o
    int n = plane >> 8;
    int o = plane & 255;
    const float4* px4 = (const float4*)(x   + (size_t)plane * 4096);
    const float4* pr4 = (const float4*)(res + (size_t)plane * 4096);
    float4*       po4 = (float4*)(out + (size_t)plane * 4096);
    __shared__ float sah[64], saw[64];
    int t = threadIdx.x;
    if (t < 128) {
        int hh  = t & 63;
        int off = (t < 64) ? 0 : 64;
        const float* wv = (t < 64) ? (w2 + o * MIP) : (w3 + o * MIP);
        float acc = (t < 64) ? b2[o] : b3[o];
        const float* ylp = yl + (size_t)n * MIP * 128 + off + hh;
#pragma unroll
        for (int m = 0; m < MIP; m++) acc += ylp[m * 128] * wv[m];
        float sig = 1.f / (1.f + __expf(-acc));
        if (t < 64) sah[hh] = sig; else saw[hh] = sig;
    }
    __syncthreads();
    const float4 sw4 = *(const float4*)&saw[4 * (t & 15)];
#pragma unroll
    for (int i = 0; i < 4; i++) {
        int row = i * 16 + (t >> 4);
        float ahr2 = 2.f * sah[row];
        float4 a = px4[i * 256 + t];
        float4 b = pr4[i * 256 + t];
        float4 oo;
        oo.x = a.x * (ahr2 * sw4.x) + 2.f * b.x;
        oo.y = a.y * (ahr2 * sw4.y) + 2.f * b.y;
        oo.z = a.z * (ahr2 * sw4.z) + 2.f * b.z;
        oo.w = a.w * (ahr2 * sw4.w) + 2.f * b.w;
        po4[i * 256 + t] = oo;
    }
}

extern "C" void kernel_launch(void* const* d_in, const int* in_sizes, int n_in,
                              void* d_out, int out_size, void* d_ws, size_t ws_size,
                              hipStream_t stream) {
    const float* x     = (const float*)d_in[0];
    const float* res   = (const float*)d_in[1];
    const float* w1    = (const float*)d_in[2];
    const float* b1    = (const float*)d_in[3];
    const float* gamma = (const float*)d_in[4];
    const float* beta  = (const float*)d_in[5];
    const float* mean  = (const float*)d_in[6];
    const float* var   = (const float*)d_in[7];
    const float* w2    = (const float*)d_in[8];
    const float* b2    = (const float*)d_in[9];
    const float* w3    = (const float*)d_in[10];
    const float* b3    = (const float*)d_in[11];
    float* out = (float*)d_out;

    float* ws = (float*)d_ws;
    float* xh = ws;                 // 16*256*64 = 262144 floats
    float* xw = ws + 262144;        // 262144 floats
    float* yl = ws + 524288;        // 16*8*128 = 16384 floats

    k_reduce<<<NB * CB, 256, 0, stream>>>(x, res, xh, xw);
    k_mid_a<<<NB, 256, 0, stream>>>(xh, xw, w1, b1, gamma, beta, mean, var, yl);
    k_apply<<<NB * CB, 256, 0, stream>>>(x, res, yl, w2, b2, w3, b3, out);
}